// Round 12
// baseline (447.771 us; speedup 1.0000x reference)
//
#include <hip/hip_runtime.h>
#include <hip/hip_bf16.h>

typedef __attribute__((ext_vector_type(8))) short bf16x8;
typedef __attribute__((ext_vector_type(16))) float f32x16;
typedef __attribute__((ext_vector_type(4))) unsigned int u32x4;

#define MFMA32(a, b, c) __builtin_amdgcn_mfma_f32_32x32x16_bf16((a), (b), (c), 0, 0, 0)

static __device__ __forceinline__ unsigned int pkbf(float lo, float hi) {
  unsigned int r;
  asm("v_cvt_pk_bf16_f32 %0, %1, %2" : "=v"(r) : "v"(lo), "v"(hi));
  return r;
}

static __device__ __forceinline__ bf16x8 u4_to_bf8(u32x4 u) {
  union { u32x4 u; bf16x8 b; } cv;
  cv.u = u;
  return cv.b;
}

static __device__ __forceinline__ f32x16 z16() {
  f32x16 z;
#pragma unroll
  for (int i = 0; i < 16; ++i) z[i] = 0.0f;
  return z;
}

// Convert one 32x32 MFMA C-tile (value at [row=(r&3)+8*(r>>2)+4*hi][col=lane&31])
// into two bf16 frags with k-runs taken from the ROW dim: f0 = rows 8*hi+{0..7},
// f1 = rows 16+8*hi+{0..7}, column (lane&31) preserved.
static __device__ __forceinline__ void tile2frag(const f32x16 t, int hi,
                                                 bf16x8* f0, bf16x8* f1) {
  unsigned int a0 = pkbf(t[0], t[1]), a1 = pkbf(t[2], t[3]);
  unsigned int b0 = pkbf(t[4], t[5]), b1 = pkbf(t[6], t[7]);
  unsigned int c0 = pkbf(t[8], t[9]), c1 = pkbf(t[10], t[11]);
  unsigned int d0 = pkbf(t[12], t[13]), d1 = pkbf(t[14], t[15]);
  unsigned int sa0 = __shfl_xor((int)a0, 32), sa1 = __shfl_xor((int)a1, 32);
  unsigned int sb0 = __shfl_xor((int)b0, 32), sb1 = __shfl_xor((int)b1, 32);
  unsigned int sc0 = __shfl_xor((int)c0, 32), sc1 = __shfl_xor((int)c1, 32);
  unsigned int sd0 = __shfl_xor((int)d0, 32), sd1 = __shfl_xor((int)d1, 32);
  u32x4 fa, fb;
  fa[0] = hi ? sb0 : a0; fa[1] = hi ? sb1 : a1;
  fa[2] = hi ? b0 : sa0; fa[3] = hi ? b1 : sa1;
  fb[0] = hi ? sd0 : c0; fb[1] = hi ? sd1 : c1;
  fb[2] = hi ? d0 : sc0; fb[3] = hi ? d1 : sc1;
  *f0 = u4_to_bf8(fa);
  *f1 = u4_to_bf8(fb);
}

// T = (X @ Wg^T + bg)^T via mfma(A=W-frags, B=X rows), SEQUENTIAL over td so only
// 2 C-tiles (32 AGPR) are live at a time. Wg pre-packed: cell (td,ke,lane)*8.
static __device__ __forceinline__ void projT(
    const unsigned short* __restrict__ Wg, const float* __restrict__ bg,
    const unsigned short* Xs, int lane, int l31, int hi, bf16x8 frag[2][4]) {
  const int sw = l31 << 3;
  const unsigned short* xr0 = Xs + l31 * 512;
  const unsigned short* xr1 = Xs + (l31 + 32) * 512;
#pragma unroll
  for (int td = 0; td < 2; ++td) {
    f32x16 c0 = z16(), c1 = z16();   // c[tq] for this td
    const unsigned short* wp = Wg + td * 16384 + lane * 8;
#pragma unroll 2
    for (int ke = 0; ke < 32; ++ke) {
      const int eo = 8 * hi + 16 * ke;
      bf16x8 x0 = *reinterpret_cast<const bf16x8*>(xr0 + (eo ^ sw));
      bf16x8 x1 = *reinterpret_cast<const bf16x8*>(xr1 + (eo ^ sw));
      bf16x8 w0 = *reinterpret_cast<const bf16x8*>(wp + ke * 512);
      c0 = MFMA32(w0, x0, c0);
      c1 = MFMA32(w0, x1, c1);
    }
    const float* bb = bg + 32 * td;
#pragma unroll
    for (int q2 = 0; q2 < 4; ++q2) {
      float4 b0 = *reinterpret_cast<const float4*>(bb + 8 * q2 + 4 * hi);
      c0[4 * q2 + 0] += b0.x; c0[4 * q2 + 1] += b0.y;
      c0[4 * q2 + 2] += b0.z; c0[4 * q2 + 3] += b0.w;
      c1[4 * q2 + 0] += b0.x; c1[4 * q2 + 1] += b0.y;
      c1[4 * q2 + 2] += b0.z; c1[4 * q2 + 3] += b0.w;
    }
    tile2frag(c0, hi, &frag[0][2 * td], &frag[0][2 * td + 1]);
    tile2frag(c1, hi, &frag[1][2 * td], &frag[1][2 * td + 1]);
  }
}

// Scale + bias/mask + softmax for one query tile. A lane holds only HALF the keys
// (hi-interleaved rows); lane l^32 holds the complement -> combine via shfl_xor(32).
static __device__ __forceinline__ float sm_tp(f32x16& t0, f32x16& t1,
                                              const float* BmRow, int swz, int hi) {
#pragma unroll
  for (int q2 = 0; q2 < 4; ++q2) {
    float4 b0 = *reinterpret_cast<const float4*>(BmRow + ((8 * q2 + 4 * hi) ^ swz));
    float4 b1 = *reinterpret_cast<const float4*>(BmRow + ((32 + 8 * q2 + 4 * hi) ^ swz));
    t0[4 * q2 + 0] = fmaf(t0[4 * q2 + 0], 0.125f, b0.x);
    t0[4 * q2 + 1] = fmaf(t0[4 * q2 + 1], 0.125f, b0.y);
    t0[4 * q2 + 2] = fmaf(t0[4 * q2 + 2], 0.125f, b0.z);
    t0[4 * q2 + 3] = fmaf(t0[4 * q2 + 3], 0.125f, b0.w);
    t1[4 * q2 + 0] = fmaf(t1[4 * q2 + 0], 0.125f, b1.x);
    t1[4 * q2 + 1] = fmaf(t1[4 * q2 + 1], 0.125f, b1.y);
    t1[4 * q2 + 2] = fmaf(t1[4 * q2 + 2], 0.125f, b1.z);
    t1[4 * q2 + 3] = fmaf(t1[4 * q2 + 3], 0.125f, b1.w);
  }
  float mx = t0[0];
#pragma unroll
  for (int r = 1; r < 16; ++r) mx = fmaxf(mx, t0[r]);
#pragma unroll
  for (int r = 0; r < 16; ++r) mx = fmaxf(mx, t1[r]);
  mx = fmaxf(mx, __shfl_xor(mx, 32));
  float sum = 0.f;
#pragma unroll
  for (int r = 0; r < 16; ++r) { t0[r] = __expf(t0[r] - mx); sum += t0[r]; }
#pragma unroll
  for (int r = 0; r < 16; ++r) { t1[r] = __expf(t1[r] - mx); sum += t1[r]; }
  sum += __shfl_xor(sum, 32);
  return 1.0f / sum;
}

// Pack fp32 weights -> bf16 frag-order: 32 blocks of [64][512] (Wq h0-7, Wk h0-7,
// Wv h0-7, Wo w0-7); cell (td,ke,lane)*8 = W[32*td+l31][16*ke+8*hi+{0..7}].
__global__ __launch_bounds__(256) void prep_weights(
    const float* __restrict__ Wq, const float* __restrict__ Wk,
    const float* __restrict__ Wv, const float* __restrict__ Wo,
    unsigned short* __restrict__ dst) {
  int i = blockIdx.x * 256 + threadIdx.x;   // 131072 cells x 8 elems
  int blk = i >> 12;
  int c = i & 4095;
  int td = c >> 11;
  int ke = (c >> 6) & 31;
  int lane = c & 63;
  int hi = lane >> 5, l31 = lane & 31;
  int row = 32 * td + l31;
  int e = 16 * ke + 8 * hi;
  int seg = blk >> 3, sub = blk & 7;
  const float* base = (seg == 0) ? Wq : (seg == 1) ? Wk : (seg == 2) ? Wv : Wo;
  const float* src = base + (size_t)(sub * 64 + row) * 512 + e;
  float4 v0 = reinterpret_cast<const float4*>(src)[0];
  float4 v1 = reinterpret_cast<const float4*>(src)[1];
  u32x4 o;
  o[0] = pkbf(v0.x, v0.y); o[1] = pkbf(v0.z, v0.w);
  o[2] = pkbf(v1.x, v1.y); o[3] = pkbf(v1.z, v1.w);
  *reinterpret_cast<u32x4*>(dst + (size_t)blk * 32768 + c * 8) = o;
}

// One block per window (2048 blocks), 512 threads = 8 waves, wave w = head w.
// LDS = 80 KiB -> 2 blocks/CU = 16 waves/CU = 4 waves/SIMD (2x round 11's
// latency hiding). Register budget 128/wave: sequential-tile phases keep
// <=32 AGPR + ~95 arch live (round-11 structure: R staged in the out slot,
// no Rs-in-LDS, no cross-barrier register state).
__global__ __launch_bounds__(512, 4) void swin_fused(
    const float* __restrict__ patches,
    const float* __restrict__ bq, const float* __restrict__ bk,
    const float* __restrict__ bv, const float* __restrict__ bo,
    const float* __restrict__ posb,
    const unsigned short* __restrict__ Wbf,
    float* __restrict__ out) {
  __shared__ unsigned short Xs[64 * 512];    // X bf16, swizzled
  __shared__ float Bm[64 * 64];              // bias+mask, granule-swizzled

  const int tid = threadIdx.x;
  const int bid = blockIdx.x;                // ((b*16+y)*16+x)
  const int wxi = bid & 15;
  const int wyi = (bid >> 4) & 15;
  const int w = tid >> 6;                    // wave 0..7
  const int lane = tid & 63;
  const int l31 = lane & 31;
  const int hi = lane >> 5;
  const int h = w;                           // one head per wave

  // ---- Phase A: stage X (fp32->bf16, 5-bit granule swizzle) + build Bm ----
  const float* Xg = patches + (size_t)bid * 32768;
#pragma unroll
  for (int it = 0; it < 8; ++it) {
    int c = tid + it * 512;
    int p = c >> 6;
    int e0 = (c & 63) << 3;
    const float4* gp = reinterpret_cast<const float4*>(Xg + p * 512 + e0);
    float4 v0 = gp[0], v1 = gp[1];
    u32x4 xv;
    xv[0] = pkbf(v0.x, v0.y); xv[1] = pkbf(v0.z, v0.w);
    xv[2] = pkbf(v1.x, v1.y); xv[3] = pkbf(v1.z, v1.w);
    *reinterpret_cast<u32x4*>(Xs + p * 512 + (e0 ^ ((p & 31) << 3))) = xv;
  }
#pragma unroll
  for (int ii = 0; ii < 8; ++ii) {
    int i = ii * 512 + tid;
    int p = i >> 6, k = i & 63;
    int pr = p >> 3, pc = p & 7, kr = k >> 3, kc = k & 7;
    float b = posb[(pr - kr + 7) * 15 + (pc - kc + 7)];
    bool mk = ((wyi == 15) && ((pr < 4) != (kr < 4))) ||
              ((wxi == 15) && ((pc < 4) != (kc < 4)));
    Bm[p * 64 + (k ^ ((p & 15) << 2))] = mk ? -1e30f : b;
  }
  __syncthreads();

  // R staging area: first 64 KiB (32768 shorts) of this window's out slot.
  unsigned short* Rws = reinterpret_cast<unsigned short*>(out) + (size_t)bid * 65536;

  // ---- Phase B: K, Q projections (td-sequential, 32 AGPR max) ----
  bf16x8 kf[2][4], qf[2][4];
  projT(Wbf + (size_t)(8 + h) * 32768, bk + h * 64, Xs, lane, l31, hi, kf);
  projT(Wbf + (size_t)(0 + h) * 32768, bq + h * 64, Xs, lane, l31, hi, qf);

  // ---- Phase C: S^T = K' Q'^T + softmax, one query-tile tp at a time ----
  bf16x8 pf[2][4];   // unnormalized exp(P) frags
  float sinv0, sinv1;
  const int bswz = (l31 & 15) << 2;
#pragma unroll
  for (int tp = 0; tp < 2; ++tp) {
    f32x16 s0 = z16(), s1 = z16();   // s[tk] for this tp
#pragma unroll
    for (int kd = 0; kd < 4; ++kd) {
      s0 = MFMA32(kf[0][kd], qf[tp][kd], s0);
      s1 = MFMA32(kf[1][kd], qf[tp][kd], s1);
    }
    float si = sm_tp(s0, s1, Bm + (l31 + 32 * tp) * 64, bswz, hi);
    if (tp == 0) sinv0 = si; else sinv1 = si;
    tile2frag(s0, hi, &pf[tp][0], &pf[tp][1]);
    tile2frag(s1, hi, &pf[tp][2], &pf[tp][3]);
  }

  // ---- Phase D/E: V proj fused with PV per td; R -> Rws immediately ----
  // Rws cell layout: [(tq*32 + ke)*64 + lane]*8 holds
  // R[p = 32*tq + l31][hd = 16*ke + 8*hi + {0..7}]; this head's ke = h*4+2*td+{0,1}.
  {
    const int sw = l31 << 3;
    const unsigned short* xr0 = Xs + l31 * 512;
    const unsigned short* xr1 = Xs + (l31 + 32) * 512;
#pragma unroll
    for (int td = 0; td < 2; ++td) {
      f32x16 c0 = z16(), c1 = z16();   // v[tq] for this td
      const unsigned short* wp = Wbf + (size_t)(16 + h) * 32768 + td * 16384 + lane * 8;
#pragma unroll 2
      for (int ke = 0; ke < 32; ++ke) {
        const int eo = 8 * hi + 16 * ke;
        bf16x8 x0 = *reinterpret_cast<const bf16x8*>(xr0 + (eo ^ sw));
        bf16x8 x1 = *reinterpret_cast<const bf16x8*>(xr1 + (eo ^ sw));
        bf16x8 w0 = *reinterpret_cast<const bf16x8*>(wp + ke * 512);
        c0 = MFMA32(x0, w0, c0);
        c1 = MFMA32(x1, w0, c1);
      }
      float bvv = bv[h * 64 + 32 * td + l31];
#pragma unroll
      for (int r = 0; r < 16; ++r) { c0[r] += bvv; c1[r] += bvv; }
      bf16x8 vf[4];   // V^T[d=l31+32td][q-run 16*ks+8*hi+{0..7}]
      tile2frag(c0, hi, &vf[0], &vf[1]);
      tile2frag(c1, hi, &vf[2], &vf[3]);
      f32x16 ra = z16(), rb = z16();   // r[td][tp=0], r[td][tp=1]
#pragma unroll
      for (int ks = 0; ks < 4; ++ks) {
        ra = MFMA32(vf[ks], pf[0][ks], ra);
        rb = MFMA32(vf[ks], pf[1][ks], rb);
      }
#pragma unroll
      for (int r = 0; r < 16; ++r) { ra[r] *= sinv0; rb[r] *= sinv1; }
      bf16x8 f0, f1;
      unsigned short* rl = Rws + lane * 8;
      tile2frag(ra, hi, &f0, &f1);   // tq=0: ke = h*4 + 2*td + {0,1}
      *reinterpret_cast<bf16x8*>(rl + (h * 4 + 2 * td + 0) * 512) = f0;
      *reinterpret_cast<bf16x8*>(rl + (h * 4 + 2 * td + 1) * 512) = f1;
      tile2frag(rb, hi, &f0, &f1);   // tq=1
      *reinterpret_cast<bf16x8*>(rl + 16384 + (h * 4 + 2 * td + 0) * 512) = f0;
      *reinterpret_cast<bf16x8*>(rl + 16384 + (h * 4 + 2 * td + 1) * 512) = f1;
    }
  }

  __syncthreads();  // drain R stores (vmcnt 0) + barrier: R visible block-wide

  // ---- Phase F: out = R @ Wo^T (+bo); wave w owns cols 64w..64w+63,
  // 2 passes (tc) of 32 cols, 2 acc tiles (32 AGPR) each. R fully consumed
  // before the fp32 out write clobbers the staging area (barrier below).
  f32x16 acc[2][2];   // [tc][tq] — compile-time indices
#pragma unroll
  for (int tc = 0; tc < 2; ++tc)
#pragma unroll
    for (int tq = 0; tq < 2; ++tq)
      acc[tc][tq] = z16();
  {
    const unsigned short* rl = Rws + lane * 8;
    const unsigned short* wp = Wbf + (size_t)(24 + w) * 32768 + lane * 8;
#pragma unroll 2
    for (int kc = 0; kc < 32; ++kc) {
      bf16x8 r0 = *reinterpret_cast<const bf16x8*>(rl + kc * 512);
      bf16x8 r1 = *reinterpret_cast<const bf16x8*>(rl + 16384 + kc * 512);
      bf16x8 wo0 = *reinterpret_cast<const bf16x8*>(wp + kc * 512);
      bf16x8 wo1 = *reinterpret_cast<const bf16x8*>(wp + 16384 + kc * 512);
      acc[0][0] = MFMA32(r0, wo0, acc[0][0]);
      acc[0][1] = MFMA32(r1, wo0, acc[0][1]);
      acc[1][0] = MFMA32(r0, wo1, acc[1][0]);
      acc[1][1] = MFMA32(r1, wo1, acc[1][1]);
    }
  }
  __syncthreads();  // all waves done READING R; slot may now be overwritten

  float* og = out + (size_t)bid * 32768;
#pragma unroll
  for (int tc = 0; tc < 2; ++tc) {
    int col0 = 64 * w + 32 * tc + l31;
    float bov = bo[col0];
#pragma unroll
    for (int tq = 0; tq < 2; ++tq) {
      const f32x16& t = acc[tc][tq];
#pragma unroll
      for (int r = 0; r < 16; ++r) {
        int p = (r & 3) + 8 * (r >> 2) + 4 * hi + 32 * tq;
        og[p * 512 + col0] = t[r] + bov;
      }
    }
  }
}

extern "C" void kernel_launch(void* const* d_in, const int* in_sizes, int n_in,
                              void* d_out, int out_size, void* d_ws, size_t ws_size,
                              hipStream_t stream) {
  const float* patches = (const float*)d_in[0];
  const float* Wq = (const float*)d_in[1];
  const float* bq = (const float*)d_in[2];
  const float* Wk = (const float*)d_in[3];
  const float* bk = (const float*)d_in[4];
  const float* Wv = (const float*)d_in[5];
  const float* bv = (const float*)d_in[6];
  const float* Wo = (const float*)d_in[7];
  const float* bo = (const float*)d_in[8];
  const float* posb = (const float*)d_in[9];
  // mask (d_in[10]) / bias_idx (d_in[11],[12]) recomputed on device.
  unsigned short* wbf = (unsigned short*)d_ws;   // 2 MiB
  hipLaunchKernelGGL(prep_weights, dim3(512), dim3(256), 0, stream, Wq, Wk, Wv, Wo, wbf);
  hipLaunchKernelGGL(swin_fused, dim3(2048), dim3(512), 0, stream,
                     patches, bq, bk, bv, bo, posb, wbf, (float*)d_out);
}